// Round 1
// baseline (193.737 us; speedup 1.0000x reference)
//
#include <hip/hip_runtime.h>
#include <stdint.h>

typedef unsigned short u16;
typedef __attribute__((ext_vector_type(8))) unsigned short u16x8;
typedef __attribute__((ext_vector_type(4))) unsigned short u16x4;
typedef __attribute__((ext_vector_type(4))) float f32x4;
typedef __attribute__((ext_vector_type(4))) float floatx4;
typedef __attribute__((ext_vector_type(8))) __bf16 bf16x8;

#define NEGS  (-1000000000.0f)
#define MINIT (-1.0e30f)

// sizes: B=8, S=1024, H=768, heads=12, d=64, 3H=2304, M=B*S=8192
// ws layout (u16 elements):
//   xbf   @ 0         (8192*768 = 6291456)
//   wqkvb @ 6291456   (2304*768 = 1769472)
//   wob   @ 8060928   ( 768*768 =  589824)
//   qbuf  @ 8650752   (96*1024*64 = 6291456)   [bh][s][d], pre-scaled by 0.125
//   kbuf  @ 14942208  (6291456)                [bh][s][d]
//   vtbuf @ 21233664  (6291456)                [bh][d][s]  (transposed V)
//   x2buf @ 27525120  (6291456)                [m][h*64+dd] attention output
// total 33816576 u16 = 67.6 MB

__device__ __forceinline__ u16 f2bf(float f) {
  union { float f; unsigned u; } c; c.f = f;
  unsigned r = c.u + 0x7fffu + ((c.u >> 16) & 1u);   // RNE
  return (u16)(r >> 16);
}

__device__ __forceinline__ bf16x8 ld_bf8(const u16* p) {
  return __builtin_bit_cast(bf16x8, *(const u16x8*)p);
}

// ---------------------------------------------------------------- convert
__global__ void convert_kernel(const float* __restrict__ x,
                               const float* __restrict__ w1,
                               const float* __restrict__ w2,
                               u16* __restrict__ xb,
                               u16* __restrict__ w1b,
                               u16* __restrict__ w2b) {
  const long NX = 6291456 / 4, NW1 = 1769472 / 4, NW2 = 589824 / 4;
  const long total = NX + NW1 + NW2;
  for (long i = (long)blockIdx.x * 256 + threadIdx.x; i < total;
       i += (long)gridDim.x * 256) {
    const float* src; u16* dst; long j;
    if (i < NX)            { src = x;  dst = xb;  j = i; }
    else if (i < NX + NW1) { src = w1; dst = w1b; j = i - NX; }
    else                   { src = w2; dst = w2b; j = i - NX - NW1; }
    floatx4 v = ((const floatx4*)src)[j];
    u16x4 o;
    o[0] = f2bf(v[0]); o[1] = f2bf(v[1]); o[2] = f2bf(v[2]); o[3] = f2bf(v[3]);
    ((u16x4*)dst)[j] = o;
  }
}

// ---------------------------------------------------------------- QKV GEMM
// C[m][n] = sum_k X[m][k]*Wqkv[n][k] + bqkv[n];  scatter into q/k/vt bufs.
__global__ __launch_bounds__(256, 2)
void qkv_gemm(const u16* __restrict__ A, const u16* __restrict__ W,
              const float* __restrict__ bias,
              u16* __restrict__ qb, u16* __restrict__ kb, u16* __restrict__ vtb) {
  __shared__ __align__(16) u16 lA[128 * 32];
  __shared__ __align__(16) u16 lB[128 * 32];
  const int tid = threadIdx.x;
  const int lane = tid & 63, wid = tid >> 6;
  const int wm = wid >> 1, wn = wid & 1;
  const int l15 = lane & 15, l4 = lane >> 4;
  const int rowA0 = blockIdx.y * 128, rowB0 = blockIdx.x * 128;
  const int K = 768;
  const int srow = tid >> 2, scol = (tid & 3) * 8;

  f32x4 acc[4][4];
  const f32x4 vz = {0.f, 0.f, 0.f, 0.f};
#pragma unroll
  for (int i = 0; i < 4; ++i)
#pragma unroll
    for (int j = 0; j < 4; ++j) acc[i][j] = vz;

  for (int k0 = 0; k0 < K; k0 += 32) {
#pragma unroll
    for (int i = 0; i < 2; ++i) {
      int r = srow + i * 64;
      *(u16x8*)(lA + r * 32 + scol) =
          *(const u16x8*)(A + (size_t)(rowA0 + r) * K + k0 + scol);
      *(u16x8*)(lB + r * 32 + scol) =
          *(const u16x8*)(W + (size_t)(rowB0 + r) * K + k0 + scol);
    }
    __syncthreads();
    bf16x8 af[4], bfr[4];
#pragma unroll
    for (int mi = 0; mi < 4; ++mi)
      af[mi] = ld_bf8(lA + (wm * 64 + mi * 16 + l15) * 32 + l4 * 8);
#pragma unroll
    for (int ni = 0; ni < 4; ++ni)
      bfr[ni] = ld_bf8(lB + (wn * 64 + ni * 16 + l15) * 32 + l4 * 8);
#pragma unroll
    for (int mi = 0; mi < 4; ++mi)
#pragma unroll
      for (int ni = 0; ni < 4; ++ni)
        acc[mi][ni] = __builtin_amdgcn_mfma_f32_16x16x32_bf16(
            af[mi], bfr[ni], acc[mi][ni], 0, 0, 0);
    __syncthreads();
  }

  // epilogue: n -> (h = n/192, t = (n%192)/64, dd = n%64)
#pragma unroll
  for (int ni = 0; ni < 4; ++ni) {
    int n = rowB0 + wn * 64 + ni * 16 + l15;
    int h = n / 192;
    int r3 = n - h * 192;
    int t = r3 >> 6, dd = r3 & 63;
    float bn_ = bias[n];
#pragma unroll
    for (int mi = 0; mi < 4; ++mi) {
#pragma unroll
      for (int r = 0; r < 4; ++r) {
        int m = rowA0 + wm * 64 + mi * 16 + l4 * 4 + r;
        int b = m >> 10, s = m & 1023;
        size_t bh = (size_t)(b * 12 + h);
        float v = acc[mi][ni][r] + bn_;
        if (t == 0)
          qb[bh * 65536 + (size_t)s * 64 + dd] = f2bf(v * 0.125f);
        else if (t == 1)
          kb[bh * 65536 + (size_t)s * 64 + dd] = f2bf(v);
        else
          vtb[bh * 65536 + (size_t)dd * 1024 + s] = f2bf(v);
      }
    }
  }
}

// ---------------------------------------------------------------- attention
// grid (96, 8): blockIdx.x = b*12+h, blockIdx.y = q-tile of 128 rows.
// 4 waves x 32 q-rows each, KV tiles of 64, online softmax, no inter-wave sync.
__global__ __launch_bounds__(256, 2)
void attn_kernel(const u16* __restrict__ qb, const u16* __restrict__ kb,
                 const u16* __restrict__ vtb, const void* __restrict__ maskp,
                 u16* __restrict__ x2) {
  const int bh = blockIdx.x, qt = blockIdx.y;
  const int b = bh / 12, h = bh - b * 12;
  const int tid = threadIdx.x;
  const int w = tid >> 6, lane = tid & 63;
  const int l15 = lane & 15, l4 = lane >> 4;

  __shared__ int mlds[1024];
  __shared__ int any_big;
  __shared__ __align__(16) u16 plds[4][32][72];  // +8 pad: bank spread

  // ---- mask staging; robust to int32 vs byte-packed bool ----
  if (tid == 0) any_big = 0;
  __syncthreads();
  {
    const unsigned* mu = (const unsigned*)maskp;
    int loc = 0;
    for (int i = tid; i < 2048; i += 256)
      if (mu[i] > 1u) loc = 1;
    if (loc) atomicOr(&any_big, 1);
  }
  __syncthreads();
  if (any_big) {  // bytes
    const unsigned char* mb = (const unsigned char*)maskp;
    for (int i = tid; i < 1024; i += 256) mlds[i] = mb[b * 1024 + i];
  } else {        // int32
    const int* mi_ = (const int*)maskp;
    for (int i = tid; i < 1024; i += 256) mlds[i] = mi_[b * 1024 + i];
  }
  __syncthreads();

  const size_t base = (size_t)bh * 65536;
  const int q0 = qt * 128 + w * 32;

  bf16x8 qf[2][2];
#pragma unroll
  for (int fr = 0; fr < 2; ++fr)
#pragma unroll
    for (int ks = 0; ks < 2; ++ks)
      qf[fr][ks] =
          ld_bf8(qb + base + (size_t)(q0 + fr * 16 + l15) * 64 + ks * 32 + l4 * 8);

  f32x4 o[2][4];
  float mr[2][4], lr[2][4];
  const f32x4 vz = {0.f, 0.f, 0.f, 0.f};
#pragma unroll
  for (int fr = 0; fr < 2; ++fr) {
#pragma unroll
    for (int oc = 0; oc < 4; ++oc) o[fr][oc] = vz;
#pragma unroll
    for (int r = 0; r < 4; ++r) { mr[fr][r] = MINIT; lr[fr][r] = 0.f; }
  }

  for (int kt = 0; kt < 16; ++kt) {
    f32x4 s[2][4];
#pragma unroll
    for (int fr = 0; fr < 2; ++fr)
#pragma unroll
      for (int nc = 0; nc < 4; ++nc) s[fr][nc] = vz;

    // S = Q K^T (scale pre-folded into Q)
#pragma unroll
    for (int nc = 0; nc < 4; ++nc) {
      int kv = kt * 64 + nc * 16 + l15;
      bf16x8 kf0 = ld_bf8(kb + base + (size_t)kv * 64 + l4 * 8);
      bf16x8 kf1 = ld_bf8(kb + base + (size_t)kv * 64 + 32 + l4 * 8);
      s[0][nc] = __builtin_amdgcn_mfma_f32_16x16x32_bf16(qf[0][0], kf0, s[0][nc], 0, 0, 0);
      s[0][nc] = __builtin_amdgcn_mfma_f32_16x16x32_bf16(qf[0][1], kf1, s[0][nc], 0, 0, 0);
      s[1][nc] = __builtin_amdgcn_mfma_f32_16x16x32_bf16(qf[1][0], kf0, s[1][nc], 0, 0, 0);
      s[1][nc] = __builtin_amdgcn_mfma_f32_16x16x32_bf16(qf[1][1], kf1, s[1][nc], 0, 0, 0);
    }
    // mask (col-only condition)
#pragma unroll
    for (int nc = 0; nc < 4; ++nc) {
      int kv = kt * 64 + nc * 16 + l15;
      if (mlds[kv] != 0) {
#pragma unroll
        for (int fr = 0; fr < 2; ++fr)
#pragma unroll
          for (int r = 0; r < 4; ++r) s[fr][nc][r] = NEGS;
      }
    }
    // wave-parallel row max (reduce across the 16-lane col group)
    float mt[2][4];
#pragma unroll
    for (int fr = 0; fr < 2; ++fr)
#pragma unroll
      for (int r = 0; r < 4; ++r) {
        float v = s[fr][0][r];
        v = fmaxf(v, s[fr][1][r]);
        v = fmaxf(v, s[fr][2][r]);
        v = fmaxf(v, s[fr][3][r]);
        mt[fr][r] = v;
      }
#pragma unroll
    for (int d = 1; d < 16; d <<= 1)
#pragma unroll
      for (int fr = 0; fr < 2; ++fr)
#pragma unroll
        for (int r = 0; r < 4; ++r)
          mt[fr][r] = fmaxf(mt[fr][r], __shfl_xor(mt[fr][r], d, 64));

    float al[2][4], ps[2][4];
#pragma unroll
    for (int fr = 0; fr < 2; ++fr)
#pragma unroll
      for (int r = 0; r < 4; ++r) {
        float mn = fmaxf(mr[fr][r], mt[fr][r]);
        al[fr][r] = __expf(mr[fr][r] - mn);
        mr[fr][r] = mn;
        ps[fr][r] = 0.f;
      }
    // P = exp(S - m), row partial sums
#pragma unroll
    for (int fr = 0; fr < 2; ++fr)
#pragma unroll
      for (int nc = 0; nc < 4; ++nc)
#pragma unroll
        for (int r = 0; r < 4; ++r) {
          float p = __expf(s[fr][nc][r] - mr[fr][r]);
          s[fr][nc][r] = p;
          ps[fr][r] += p;
        }
#pragma unroll
    for (int d = 1; d < 16; d <<= 1)
#pragma unroll
      for (int fr = 0; fr < 2; ++fr)
#pragma unroll
        for (int r = 0; r < 4; ++r)
          ps[fr][r] += __shfl_xor(ps[fr][r], d, 64);
#pragma unroll
    for (int fr = 0; fr < 2; ++fr)
#pragma unroll
      for (int r = 0; r < 4; ++r) lr[fr][r] = lr[fr][r] * al[fr][r] + ps[fr][r];
    // rescale O
#pragma unroll
    for (int fr = 0; fr < 2; ++fr)
#pragma unroll
      for (int oc = 0; oc < 4; ++oc)
#pragma unroll
        for (int r = 0; r < 4; ++r) o[fr][oc][r] *= al[fr][r];

    // P (C-layout) -> LDS -> A-layout fragments (wave-private, DS in-order)
#pragma unroll
    for (int fr = 0; fr < 2; ++fr)
#pragma unroll
      for (int nc = 0; nc < 4; ++nc)
#pragma unroll
        for (int r = 0; r < 4; ++r)
          plds[w][fr * 16 + l4 * 4 + r][nc * 16 + l15] = f2bf(s[fr][nc][r]);
    bf16x8 pf[2][2];
#pragma unroll
    for (int fr = 0; fr < 2; ++fr)
#pragma unroll
      for (int ks = 0; ks < 2; ++ks)
        pf[fr][ks] = ld_bf8(&plds[w][fr * 16 + l15][ks * 32 + l4 * 8]);

    // O += P V   (V^T layout makes B-frags contiguous)
#pragma unroll
    for (int oc = 0; oc < 4; ++oc) {
      const u16* vp = vtb + base + (size_t)(oc * 16 + l15) * 1024 + kt * 64 + l4 * 8;
      bf16x8 vf0 = ld_bf8(vp);
      bf16x8 vf1 = ld_bf8(vp + 32);
      o[0][oc] = __builtin_amdgcn_mfma_f32_16x16x32_bf16(pf[0][0], vf0, o[0][oc], 0, 0, 0);
      o[0][oc] = __builtin_amdgcn_mfma_f32_16x16x32_bf16(pf[0][1], vf1, o[0][oc], 0, 0, 0);
      o[1][oc] = __builtin_amdgcn_mfma_f32_16x16x32_bf16(pf[1][0], vf0, o[1][oc], 0, 0, 0);
      o[1][oc] = __builtin_amdgcn_mfma_f32_16x16x32_bf16(pf[1][1], vf1, o[1][oc], 0, 0, 0);
    }
  }

  // finalize: divide by row sums, write x2[m][h*64+col] as bf16
#pragma unroll
  for (int fr = 0; fr < 2; ++fr) {
    float inv[4];
#pragma unroll
    for (int r = 0; r < 4; ++r) inv[r] = 1.0f / lr[fr][r];
#pragma unroll
    for (int oc = 0; oc < 4; ++oc)
#pragma unroll
      for (int r = 0; r < 4; ++r) {
        int row = q0 + fr * 16 + l4 * 4 + r;
        int m = b * 1024 + row;
        int col = h * 64 + oc * 16 + l15;
        x2[(size_t)m * 768 + col] = f2bf(o[fr][oc][r] * inv[r]);
      }
  }
}

// ---------------------------------------------------------------- out proj
__global__ __launch_bounds__(256, 2)
void out_gemm(const u16* __restrict__ A, const u16* __restrict__ W,
              const float* __restrict__ bias, float* __restrict__ out) {
  __shared__ __align__(16) u16 lA[128 * 32];
  __shared__ __align__(16) u16 lB[128 * 32];
  const int tid = threadIdx.x;
  const int lane = tid & 63, wid = tid >> 6;
  const int wm = wid >> 1, wn = wid & 1;
  const int l15 = lane & 15, l4 = lane >> 4;
  const int rowA0 = blockIdx.y * 128, rowB0 = blockIdx.x * 128;
  const int K = 768;
  const int srow = tid >> 2, scol = (tid & 3) * 8;

  f32x4 acc[4][4];
  const f32x4 vz = {0.f, 0.f, 0.f, 0.f};
#pragma unroll
  for (int i = 0; i < 4; ++i)
#pragma unroll
    for (int j = 0; j < 4; ++j) acc[i][j] = vz;

  for (int k0 = 0; k0 < K; k0 += 32) {
#pragma unroll
    for (int i = 0; i < 2; ++i) {
      int r = srow + i * 64;
      *(u16x8*)(lA + r * 32 + scol) =
          *(const u16x8*)(A + (size_t)(rowA0 + r) * K + k0 + scol);
      *(u16x8*)(lB + r * 32 + scol) =
          *(const u16x8*)(W + (size_t)(rowB0 + r) * K + k0 + scol);
    }
    __syncthreads();
    bf16x8 af[4], bfr[4];
#pragma unroll
    for (int mi = 0; mi < 4; ++mi)
      af[mi] = ld_bf8(lA + (wm * 64 + mi * 16 + l15) * 32 + l4 * 8);
#pragma unroll
    for (int ni = 0; ni < 4; ++ni)
      bfr[ni] = ld_bf8(lB + (wn * 64 + ni * 16 + l15) * 32 + l4 * 8);
#pragma unroll
    for (int mi = 0; mi < 4; ++mi)
#pragma unroll
      for (int ni = 0; ni < 4; ++ni)
        acc[mi][ni] = __builtin_amdgcn_mfma_f32_16x16x32_bf16(
            af[mi], bfr[ni], acc[mi][ni], 0, 0, 0);
    __syncthreads();
  }

#pragma unroll
  for (int ni = 0; ni < 4; ++ni) {
    int n = rowB0 + wn * 64 + ni * 16 + l15;
    float bn_ = bias[n];
#pragma unroll
    for (int mi = 0; mi < 4; ++mi)
#pragma unroll
      for (int r = 0; r < 4; ++r) {
        int m = rowA0 + wm * 64 + mi * 16 + l4 * 4 + r;
        out[(size_t)m * 768 + n] = acc[mi][ni][r] + bn_;
      }
  }
}

// ---------------------------------------------------------------- launch
extern "C" void kernel_launch(void* const* d_in, const int* in_sizes, int n_in,
                              void* d_out, int out_size, void* d_ws, size_t ws_size,
                              hipStream_t stream) {
  const float* x    = (const float*)d_in[0];
  const void*  mask = d_in[1];
  const float* wqkv = (const float*)d_in[2];
  const float* bqkv = (const float*)d_in[3];
  const float* wo   = (const float*)d_in[4];
  const float* bo   = (const float*)d_in[5];
  float* out = (float*)d_out;

  u16* ws = (u16*)d_ws;
  u16* xbf   = ws;
  u16* wqkvb = ws + 6291456;
  u16* wob   = ws + 8060928;
  u16* qbuf  = ws + 8650752;
  u16* kbuf  = ws + 14942208;
  u16* vtbuf = ws + 21233664;
  u16* x2buf = ws + 27525120;

  convert_kernel<<<2048, 256, 0, stream>>>(x, wqkv, wo, xbf, wqkvb, wob);
  qkv_gemm<<<dim3(18, 64), 256, 0, stream>>>(xbf, wqkvb, bqkv, qbuf, kbuf, vtbuf);
  attn_kernel<<<dim3(96, 8), 256, 0, stream>>>(qbuf, kbuf, vtbuf, mask, x2buf);
  out_gemm<<<dim3(6, 64), 256, 0, stream>>>(x2buf, wob, bo, out);
}

// Round 2
// 189.540 us; speedup vs baseline: 1.0221x; 1.0221x over previous
//
#include <hip/hip_runtime.h>
#include <stdint.h>

typedef unsigned short u16;
typedef __attribute__((ext_vector_type(8))) unsigned short u16x8;
typedef __attribute__((ext_vector_type(4))) unsigned short u16x4;
typedef __attribute__((ext_vector_type(4))) float f32x4;
typedef __attribute__((ext_vector_type(4))) float floatx4;
typedef __attribute__((ext_vector_type(8))) __bf16 bf16x8;

// sizes: B=8, S=1024, H=768, heads=12, d=64, 3H=2304, M=B*S=8192
// ws layout (u16 elements):
//   xbf   @ 0         (6291456)
//   wqkvb @ 6291456   (1769472)
//   wob   @ 8060928   ( 589824)
//   qbuf  @ 8650752   (6291456)  [bh][s][d], pre-scaled by 0.125*log2(e)
//   kbuf  @ 14942208  (6291456)  [bh][s][d]
//   vtbuf @ 21233664  (6291456)  [bh][d][s]  (transposed V)
//   x2buf @ 27525120  (6291456)  [m][h*64+dd] attention output

__device__ __forceinline__ u16 f2bf(float f) {
  union { float f; unsigned u; } c; c.f = f;
  unsigned r = c.u + 0x7fffu + ((c.u >> 16) & 1u);   // RNE
  return (u16)(r >> 16);
}

__device__ __forceinline__ bf16x8 ld_bf8(const u16* p) {
  return __builtin_bit_cast(bf16x8, *(const u16x8*)p);
}

__device__ __forceinline__ float fexp2(float x) {
#if __has_builtin(__builtin_amdgcn_exp2f)
  return __builtin_amdgcn_exp2f(x);
#else
  float r; asm("v_exp_f32 %0, %1" : "=v"(r) : "v"(x)); return r;
#endif
}

// async global->LDS, 16 B per lane; LDS dest = base + lane*16
__device__ __forceinline__ void glds16(const void* g, void* l) {
  __builtin_amdgcn_global_load_lds(
      (const __attribute__((address_space(1))) void*)g,
      (__attribute__((address_space(3))) void*)l, 16, 0, 0);
}

// ---------------------------------------------------------------- convert
__global__ void convert_kernel(const float* __restrict__ x,
                               const float* __restrict__ w1,
                               const float* __restrict__ w2,
                               u16* __restrict__ xb,
                               u16* __restrict__ w1b,
                               u16* __restrict__ w2b) {
  const long NX = 6291456 / 4, NW1 = 1769472 / 4, NW2 = 589824 / 4;
  const long total = NX + NW1 + NW2;
  for (long i = (long)blockIdx.x * 256 + threadIdx.x; i < total;
       i += (long)gridDim.x * 256) {
    const float* src; u16* dst; long j;
    if (i < NX)            { src = x;  dst = xb;  j = i; }
    else if (i < NX + NW1) { src = w1; dst = w1b; j = i - NX; }
    else                   { src = w2; dst = w2b; j = i - NX - NW1; }
    floatx4 v = ((const floatx4*)src)[j];
    u16x4 o;
    o[0] = f2bf(v[0]); o[1] = f2bf(v[1]); o[2] = f2bf(v[2]); o[3] = f2bf(v[3]);
    ((u16x4*)dst)[j] = o;
  }
}

// ---------------------------------------------------------------- QKV GEMM
__global__ __launch_bounds__(256, 2)
void qkv_gemm(const u16* __restrict__ A, const u16* __restrict__ W,
              const float* __restrict__ bias,
              u16* __restrict__ qb, u16* __restrict__ kb, u16* __restrict__ vtb) {
  __shared__ __align__(16) u16 lA[128 * 32];
  __shared__ __align__(16) u16 lB[128 * 32];
  const int tid = threadIdx.x;
  const int lane = tid & 63, wid = tid >> 6;
  const int wm = wid >> 1, wn = wid & 1;
  const int l15 = lane & 15, l4 = lane >> 4;
  const int rowA0 = blockIdx.y * 128, rowB0 = blockIdx.x * 128;

  // staging addresses: wave wid covers rows wid*32 .. wid*32+31 (2 calls x 16 rows)
  const u16* ga = A + (size_t)(rowA0 + wid * 32 + (lane >> 2)) * 768 + (lane & 3) * 8;
  const u16* gb = W + (size_t)(rowB0 + wid * 32 + (lane >> 2)) * 768 + (lane & 3) * 8;
  u16* la0 = lA + wid * 1024;
  u16* lb0 = lB + wid * 1024;

  f32x4 acc[4][4];
  const f32x4 vz = {0.f, 0.f, 0.f, 0.f};
#pragma unroll
  for (int i = 0; i < 4; ++i)
#pragma unroll
    for (int j = 0; j < 4; ++j) acc[i][j] = vz;

  for (int k0 = 0; k0 < 768; k0 += 32) {
    glds16(ga + k0,            la0);
    glds16(ga + k0 + 16 * 768, la0 + 512);
    glds16(gb + k0,            lb0);
    glds16(gb + k0 + 16 * 768, lb0 + 512);
    __syncthreads();
    bf16x8 af[4], bfr[4];
#pragma unroll
    for (int mi = 0; mi < 4; ++mi)
      af[mi] = ld_bf8(lA + (wm * 64 + mi * 16 + l15) * 32 + l4 * 8);
#pragma unroll
    for (int ni = 0; ni < 4; ++ni)
      bfr[ni] = ld_bf8(lB + (wn * 64 + ni * 16 + l15) * 32 + l4 * 8);
#pragma unroll
    for (int mi = 0; mi < 4; ++mi)
#pragma unroll
      for (int ni = 0; ni < 4; ++ni)
        acc[mi][ni] = __builtin_amdgcn_mfma_f32_16x16x32_bf16(
            af[mi], bfr[ni], acc[mi][ni], 0, 0, 0);
    __syncthreads();
  }

  // epilogue: n -> (h = n/192, t = (n%192)/64, dd = n%64)
  const float QSC = 0.125f * 1.44269504088896f;  // fold 1/sqrt(d) * log2(e)
#pragma unroll
  for (int ni = 0; ni < 4; ++ni) {
    int n = rowB0 + wn * 64 + ni * 16 + l15;
    int h = n / 192;
    int r3 = n - h * 192;
    int t = r3 >> 6, dd = r3 & 63;
    float bn_ = bias[n];
#pragma unroll
    for (int mi = 0; mi < 4; ++mi) {
#pragma unroll
      for (int r = 0; r < 4; ++r) {
        int m = rowA0 + wm * 64 + mi * 16 + l4 * 4 + r;
        int b = m >> 10, s = m & 1023;
        size_t bh = (size_t)(b * 12 + h);
        float v = acc[mi][ni][r] + bn_;
        if (t == 0)
          qb[bh * 65536 + (size_t)s * 64 + dd] = f2bf(v * QSC);
        else if (t == 1)
          kb[bh * 65536 + (size_t)s * 64 + dd] = f2bf(v);
        else
          vtb[bh * 65536 + (size_t)dd * 1024 + s] = f2bf(v);
      }
    }
  }
}

// ---------------------------------------------------------------- attention
// grid (96, 8), 512 threads = 8 waves. wave w: qg=w&3 (32 q-rows), half=w>>2
// (8 KV tiles of 64). Static-max softmax: p = exp2(s2 - 16*log2e + maskbias),
// O and l are pure sums -> kv-split combines by addition at the end.
__global__ __launch_bounds__(512, 4)
void attn_kernel(const u16* __restrict__ qb, const u16* __restrict__ kb,
                 const u16* __restrict__ vtb, const void* __restrict__ maskp,
                 u16* __restrict__ x2) {
  const int bh = blockIdx.x, qt = blockIdx.y;
  const int b = bh / 12, h = bh - b * 12;
  const int tid = threadIdx.x;
  const int w = tid >> 6, lane = tid & 63;
  const int l15 = lane & 15, l4 = lane >> 4;
  const int qg = w & 3, half = w >> 2;

  __shared__ float mbias[1024];
  __shared__ int any_big;
  __shared__ __align__(16) u16 plds[8][32][72];      // 36864 B, per-wave P tiles
  float* obuf = (float*)&plds[0][0][0];              // reused: [128][68] f32

  // ---- mask -> additive exp2-domain bias (robust to int32 vs byte bool) ----
  if (tid == 0) any_big = 0;
  __syncthreads();
  {
    const unsigned* mu = (const unsigned*)maskp;
    int loc = 0;
    for (int i = tid; i < 2048; i += 512)
      if (mu[i] > 1u) loc = 1;
    if (loc) atomicOr(&any_big, 1);
  }
  __syncthreads();
  const float CEXP = 23.0831206542234f;  // 16 * log2(e)
  if (any_big) {
    const unsigned char* mb = (const unsigned char*)maskp;
    for (int i = tid; i < 1024; i += 512)
      mbias[i] = mb[b * 1024 + i] ? -100000.0f : -CEXP;
  } else {
    const int* mi_ = (const int*)maskp;
    for (int i = tid; i < 1024; i += 512)
      mbias[i] = mi_[b * 1024 + i] ? -100000.0f : -CEXP;
  }
  __syncthreads();

  const size_t base = (size_t)bh * 65536;
  const int q0 = qt * 128 + qg * 32;

  bf16x8 qf[2][2];
#pragma unroll
  for (int fr = 0; fr < 2; ++fr)
#pragma unroll
    for (int ks = 0; ks < 2; ++ks)
      qf[fr][ks] =
          ld_bf8(qb + base + (size_t)(q0 + fr * 16 + l15) * 64 + ks * 32 + l4 * 8);

  f32x4 o[2][4];
  float ps[2][4];
  const f32x4 vz = {0.f, 0.f, 0.f, 0.f};
#pragma unroll
  for (int fr = 0; fr < 2; ++fr) {
#pragma unroll
    for (int oc = 0; oc < 4; ++oc) o[fr][oc] = vz;
#pragma unroll
    for (int r = 0; r < 4; ++r) ps[fr][r] = 0.f;
  }

  for (int kt = half * 8; kt < half * 8 + 8; ++kt) {
    float mb4[4];
#pragma unroll
    for (int nc = 0; nc < 4; ++nc) mb4[nc] = mbias[kt * 64 + nc * 16 + l15];

    f32x4 s[2][4];
#pragma unroll
    for (int fr = 0; fr < 2; ++fr)
#pragma unroll
      for (int nc = 0; nc < 4; ++nc) s[fr][nc] = vz;

    // S = Q K^T (0.125*log2e pre-folded into Q)
#pragma unroll
    for (int nc = 0; nc < 4; ++nc) {
      int kv = kt * 64 + nc * 16 + l15;
      bf16x8 kf0 = ld_bf8(kb + base + (size_t)kv * 64 + l4 * 8);
      bf16x8 kf1 = ld_bf8(kb + base + (size_t)kv * 64 + 32 + l4 * 8);
      s[0][nc] = __builtin_amdgcn_mfma_f32_16x16x32_bf16(qf[0][0], kf0, s[0][nc], 0, 0, 0);
      s[0][nc] = __builtin_amdgcn_mfma_f32_16x16x32_bf16(qf[0][1], kf1, s[0][nc], 0, 0, 0);
      s[1][nc] = __builtin_amdgcn_mfma_f32_16x16x32_bf16(qf[1][0], kf0, s[1][nc], 0, 0, 0);
      s[1][nc] = __builtin_amdgcn_mfma_f32_16x16x32_bf16(qf[1][1], kf1, s[1][nc], 0, 0, 0);
    }

    // p = exp2(s + bias); accumulate row partial sums; stage P to LDS (bf16)
#pragma unroll
    for (int fr = 0; fr < 2; ++fr)
#pragma unroll
      for (int nc = 0; nc < 4; ++nc) {
        float mbn = mb4[nc];
#pragma unroll
        for (int r = 0; r < 4; ++r) {
          float p = fexp2(s[fr][nc][r] + mbn);
          ps[fr][r] += p;
          plds[w][fr * 16 + l4 * 4 + r][nc * 16 + l15] = f2bf(p);
        }
      }

    bf16x8 pf[2][2];
#pragma unroll
    for (int fr = 0; fr < 2; ++fr)
#pragma unroll
      for (int ks = 0; ks < 2; ++ks)
        pf[fr][ks] = ld_bf8(&plds[w][fr * 16 + l15][ks * 32 + l4 * 8]);

    // O += P V
#pragma unroll
    for (int oc = 0; oc < 4; ++oc) {
      const u16* vp = vtb + base + (size_t)(oc * 16 + l15) * 1024 + kt * 64 + l4 * 8;
      bf16x8 vf0 = ld_bf8(vp);
      bf16x8 vf1 = ld_bf8(vp + 32);
      o[0][oc] = __builtin_amdgcn_mfma_f32_16x16x32_bf16(pf[0][0], vf0, o[0][oc], 0, 0, 0);
      o[0][oc] = __builtin_amdgcn_mfma_f32_16x16x32_bf16(pf[0][1], vf1, o[0][oc], 0, 0, 0);
      o[1][oc] = __builtin_amdgcn_mfma_f32_16x16x32_bf16(pf[1][0], vf0, o[1][oc], 0, 0, 0);
      o[1][oc] = __builtin_amdgcn_mfma_f32_16x16x32_bf16(pf[1][1], vf1, o[1][oc], 0, 0, 0);
    }
  }

  // one-time row-sum reduce across the 16-lane column group
#pragma unroll
  for (int d = 1; d < 16; d <<= 1)
#pragma unroll
    for (int fr = 0; fr < 2; ++fr)
#pragma unroll
      for (int r = 0; r < 4; ++r)
        ps[fr][r] += __shfl_xor(ps[fr][r], d, 64);

  // ---- combine the two kv-halves via LDS (obuf overlays plds) ----
  __syncthreads();
  const int ro = qg * 32;
  if (half == 1) {
#pragma unroll
    for (int fr = 0; fr < 2; ++fr) {
#pragma unroll
      for (int oc = 0; oc < 4; ++oc)
#pragma unroll
        for (int r = 0; r < 4; ++r)
          obuf[(ro + fr * 16 + l4 * 4 + r) * 68 + oc * 16 + l15] = o[fr][oc][r];
      if (l15 == 0)
#pragma unroll
        for (int r = 0; r < 4; ++r)
          obuf[(ro + fr * 16 + l4 * 4 + r) * 68 + 64] = ps[fr][r];
    }
  }
  __syncthreads();
  if (half == 0) {
#pragma unroll
    for (int fr = 0; fr < 2; ++fr) {
      float inv[4];
#pragma unroll
      for (int r = 0; r < 4; ++r) {
        float lb = obuf[(ro + fr * 16 + l4 * 4 + r) * 68 + 64];
        inv[r] = 1.0f / (ps[fr][r] + lb);
      }
#pragma unroll
      for (int oc = 0; oc < 4; ++oc)
#pragma unroll
        for (int r = 0; r < 4; ++r) {
          int idx = (ro + fr * 16 + l4 * 4 + r) * 68 + oc * 16 + l15;
          obuf[idx] = (o[fr][oc][r] + obuf[idx]) * inv[r];
        }
    }
  }
  __syncthreads();

  // vectorized output: 512 threads, each handles 16 contiguous d of one row
  {
    int row = tid >> 2, q4 = tid & 3;
    const float* src = obuf + row * 68 + q4 * 16;
    u16x8 a, bv;
#pragma unroll
    for (int j = 0; j < 8; ++j) { a[j] = f2bf(src[j]); bv[j] = f2bf(src[8 + j]); }
    size_t m = (size_t)(b * 1024 + qt * 128 + row);
    u16* dst = x2 + m * 768 + h * 64 + q4 * 16;
    *(u16x8*)dst = a;
    *(u16x8*)(dst + 8) = bv;
  }
}

// ---------------------------------------------------------------- out proj
__global__ __launch_bounds__(256, 2)
void out_gemm(const u16* __restrict__ A, const u16* __restrict__ W,
              const float* __restrict__ bias, float* __restrict__ out) {
  __shared__ __align__(16) u16 lA[128 * 32];
  __shared__ __align__(16) u16 lB[128 * 32];
  const int tid = threadIdx.x;
  const int lane = tid & 63, wid = tid >> 6;
  const int wm = wid >> 1, wn = wid & 1;
  const int l15 = lane & 15, l4 = lane >> 4;
  const int rowA0 = blockIdx.y * 128, rowB0 = blockIdx.x * 128;

  const u16* ga = A + (size_t)(rowA0 + wid * 32 + (lane >> 2)) * 768 + (lane & 3) * 8;
  const u16* gb = W + (size_t)(rowB0 + wid * 32 + (lane >> 2)) * 768 + (lane & 3) * 8;
  u16* la0 = lA + wid * 1024;
  u16* lb0 = lB + wid * 1024;

  f32x4 acc[4][4];
  const f32x4 vz = {0.f, 0.f, 0.f, 0.f};
#pragma unroll
  for (int i = 0; i < 4; ++i)
#pragma unroll
    for (int j = 0; j < 4; ++j) acc[i][j] = vz;

  for (int k0 = 0; k0 < 768; k0 += 32) {
    glds16(ga + k0,            la0);
    glds16(ga + k0 + 16 * 768, la0 + 512);
    glds16(gb + k0,            lb0);
    glds16(gb + k0 + 16 * 768, lb0 + 512);
    __syncthreads();
    bf16x8 af[4], bfr[4];
#pragma unroll
    for (int mi = 0; mi < 4; ++mi)
      af[mi] = ld_bf8(lA + (wm * 64 + mi * 16 + l15) * 32 + l4 * 8);
#pragma unroll
    for (int ni = 0; ni < 4; ++ni)
      bfr[ni] = ld_bf8(lB + (wn * 64 + ni * 16 + l15) * 32 + l4 * 8);
#pragma unroll
    for (int mi = 0; mi < 4; ++mi)
#pragma unroll
      for (int ni = 0; ni < 4; ++ni)
        acc[mi][ni] = __builtin_amdgcn_mfma_f32_16x16x32_bf16(
            af[mi], bfr[ni], acc[mi][ni], 0, 0, 0);
    __syncthreads();
  }

#pragma unroll
  for (int ni = 0; ni < 4; ++ni) {
    int n = rowB0 + wn * 64 + ni * 16 + l15;
    float bn_ = bias[n];
#pragma unroll
    for (int mi = 0; mi < 4; ++mi)
#pragma unroll
      for (int r = 0; r < 4; ++r) {
        int m = rowA0 + wm * 64 + mi * 16 + l4 * 4 + r;
        out[(size_t)m * 768 + n] = acc[mi][ni][r] + bn_;
      }
  }
}

// ---------------------------------------------------------------- launch
extern "C" void kernel_launch(void* const* d_in, const int* in_sizes, int n_in,
                              void* d_out, int out_size, void* d_ws, size_t ws_size,
                              hipStream_t stream) {
  const float* x    = (const float*)d_in[0];
  const void*  mask = d_in[1];
  const float* wqkv = (const float*)d_in[2];
  const float* bqkv = (const float*)d_in[3];
  const float* wo   = (const float*)d_in[4];
  const float* bo   = (const float*)d_in[5];
  float* out = (float*)d_out;

  u16* ws = (u16*)d_ws;
  u16* xbf   = ws;
  u16* wqkvb = ws + 6291456;
  u16* wob   = ws + 8060928;
  u16* qbuf  = ws + 8650752;
  u16* kbuf  = ws + 14942208;
  u16* vtbuf = ws + 21233664;
  u16* x2buf = ws + 27525120;

  convert_kernel<<<2048, 256, 0, stream>>>(x, wqkv, wo, xbf, wqkvb, wob);
  qkv_gemm<<<dim3(18, 64), 256, 0, stream>>>(xbf, wqkvb, bqkv, qbuf, kbuf, vtbuf);
  attn_kernel<<<dim3(96, 8), 512, 0, stream>>>(qbuf, kbuf, vtbuf, mask, x2buf);
  out_gemm<<<dim3(6, 64), 256, 0, stream>>>(x2buf, wob, bo, out);
}

// Round 3
// 164.183 us; speedup vs baseline: 1.1800x; 1.1544x over previous
//
#include <hip/hip_runtime.h>
#include <stdint.h>

typedef unsigned short u16;
typedef __attribute__((ext_vector_type(8))) unsigned short u16x8;
typedef __attribute__((ext_vector_type(4))) unsigned short u16x4;
typedef __attribute__((ext_vector_type(4))) float f32x4;
typedef __attribute__((ext_vector_type(4))) float floatx4;
typedef __attribute__((ext_vector_type(8))) __bf16 bf16x8;

// sizes: B=8, S=1024, H=768, heads=12, d=64, 3H=2304, M=B*S=8192
// ws layout (u16 elements):
//   xbf   @ 0         (6291456)
//   wqkvb @ 6291456   (1769472)
//   wob   @ 8060928   ( 589824)
//   qbuf  @ 8650752   (6291456)  [bh][s][d], pre-scaled by 0.125*log2(e)
//   kbuf  @ 14942208  (6291456)  [bh][s][d]
//   vtbuf @ 21233664  (6291456)  [bh][d][s]  (transposed V)
//   x2buf @ 27525120  (6291456)  [m][h*64+dd] attention output

__device__ __forceinline__ u16 f2bf(float f) {
  union { float f; unsigned u; } c; c.f = f;
  unsigned r = c.u + 0x7fffu + ((c.u >> 16) & 1u);   // RNE
  return (u16)(r >> 16);
}

__device__ __forceinline__ bf16x8 ld_bf8(const u16* p) {
  return __builtin_bit_cast(bf16x8, *(const u16x8*)p);
}

__device__ __forceinline__ float fexp2(float x) {
#if __has_builtin(__builtin_amdgcn_exp2f)
  return __builtin_amdgcn_exp2f(x);
#else
  float r; asm("v_exp_f32 %0, %1" : "=v"(r) : "v"(x)); return r;
#endif
}

// async global->LDS, 16 B per lane; LDS dest = wave-uniform base + lane*16
__device__ __forceinline__ void glds16(const void* g, void* l) {
  __builtin_amdgcn_global_load_lds(
      (const __attribute__((address_space(1))) void*)g,
      (__attribute__((address_space(3))) void*)l, 16, 0, 0);
}

// ---------------------------------------------------------------- convert
__global__ void convert_kernel(const float* __restrict__ x,
                               const float* __restrict__ w1,
                               const float* __restrict__ w2,
                               u16* __restrict__ xb,
                               u16* __restrict__ w1b,
                               u16* __restrict__ w2b) {
  const long NX = 6291456 / 4, NW1 = 1769472 / 4, NW2 = 589824 / 4;
  const long total = NX + NW1 + NW2;
  for (long i = (long)blockIdx.x * 256 + threadIdx.x; i < total;
       i += (long)gridDim.x * 256) {
    const float* src; u16* dst; long j;
    if (i < NX)            { src = x;  dst = xb;  j = i; }
    else if (i < NX + NW1) { src = w1; dst = w1b; j = i - NX; }
    else                   { src = w2; dst = w2b; j = i - NX - NW1; }
    floatx4 v = ((const floatx4*)src)[j];
    u16x4 o;
    o[0] = f2bf(v[0]); o[1] = f2bf(v[1]); o[2] = f2bf(v[2]); o[3] = f2bf(v[3]);
    ((u16x4*)dst)[j] = o;
  }
}

// ---------------------------------------------------------------- QKV GEMM
__global__ __launch_bounds__(256, 2)
void qkv_gemm(const u16* __restrict__ A, const u16* __restrict__ W,
              const float* __restrict__ bias,
              u16* __restrict__ qb, u16* __restrict__ kb, u16* __restrict__ vtb) {
  __shared__ __align__(16) u16 lA[128 * 32];
  __shared__ __align__(16) u16 lB[128 * 32];
  const int tid = threadIdx.x;
  const int lane = tid & 63, wid = tid >> 6;
  const int wm = wid >> 1, wn = wid & 1;
  const int l15 = lane & 15, l4 = lane >> 4;
  const int rowA0 = blockIdx.y * 128, rowB0 = blockIdx.x * 128;

  const u16* ga = A + (size_t)(rowA0 + wid * 32 + (lane >> 2)) * 768 + (lane & 3) * 8;
  const u16* gb = W + (size_t)(rowB0 + wid * 32 + (lane >> 2)) * 768 + (lane & 3) * 8;
  u16* la0 = lA + wid * 1024;
  u16* lb0 = lB + wid * 1024;

  f32x4 acc[4][4];
  const f32x4 vz = {0.f, 0.f, 0.f, 0.f};
#pragma unroll
  for (int i = 0; i < 4; ++i)
#pragma unroll
    for (int j = 0; j < 4; ++j) acc[i][j] = vz;

  for (int k0 = 0; k0 < 768; k0 += 32) {
    glds16(ga + k0,            la0);
    glds16(ga + k0 + 16 * 768, la0 + 512);
    glds16(gb + k0,            lb0);
    glds16(gb + k0 + 16 * 768, lb0 + 512);
    __syncthreads();
    bf16x8 af[4], bfr[4];
#pragma unroll
    for (int mi = 0; mi < 4; ++mi)
      af[mi] = ld_bf8(lA + (wm * 64 + mi * 16 + l15) * 32 + l4 * 8);
#pragma unroll
    for (int ni = 0; ni < 4; ++ni)
      bfr[ni] = ld_bf8(lB + (wn * 64 + ni * 16 + l15) * 32 + l4 * 8);
#pragma unroll
    for (int mi = 0; mi < 4; ++mi)
#pragma unroll
      for (int ni = 0; ni < 4; ++ni)
        acc[mi][ni] = __builtin_amdgcn_mfma_f32_16x16x32_bf16(
            af[mi], bfr[ni], acc[mi][ni], 0, 0, 0);
    __syncthreads();
  }

  // epilogue: n -> (h = n/192, t = (n%192)/64, dd = n%64)
  const float QSC = 0.125f * 1.44269504088896f;  // fold 1/sqrt(d) * log2(e)
#pragma unroll
  for (int ni = 0; ni < 4; ++ni) {
    int n = rowB0 + wn * 64 + ni * 16 + l15;
    int h = n / 192;
    int r3 = n - h * 192;
    int t = r3 >> 6, dd = r3 & 63;
    float bn_ = bias[n];
#pragma unroll
    for (int mi = 0; mi < 4; ++mi) {
#pragma unroll
      for (int r = 0; r < 4; ++r) {
        int m = rowA0 + wm * 64 + mi * 16 + l4 * 4 + r;
        int b = m >> 10, s = m & 1023;
        size_t bh = (size_t)(b * 12 + h);
        float v = acc[mi][ni][r] + bn_;
        if (t == 0)
          qb[bh * 65536 + (size_t)s * 64 + dd] = f2bf(v * QSC);
        else if (t == 1)
          kb[bh * 65536 + (size_t)s * 64 + dd] = f2bf(v);
        else
          vtb[bh * 65536 + (size_t)dd * 1024 + s] = f2bf(v);
      }
    }
  }
}

// ---------------------------------------------------------------- attention
// grid (96, 8), 256 threads = 4 waves. Wave w owns q-rows qt*128+w*32..+31 and
// iterates all 16 KV tiles. Per tile, the 4 waves cooperatively stage K (8KB)
// and V^T (8KB) into double-buffered LDS via async global_load_lds; the global
// source column index is pre-swizzled (col16 ^= row&7) so the linear LDS dest
// ends up XOR-swizzled -> conflict-free ds_read_b128 on both K and V.
// Static-max softmax: p = exp2(s2 + maskbias), maskbias = -16*log2e or -1e5.
__global__ __launch_bounds__(256, 3)
void attn_kernel(const u16* __restrict__ qb, const u16* __restrict__ kb,
                 const u16* __restrict__ vtb, const void* __restrict__ maskp,
                 u16* __restrict__ x2) {
  const int bh = blockIdx.x, qt = blockIdx.y;
  const int b = bh / 12, h = bh - b * 12;
  const int tid = threadIdx.x;
  const int w = tid >> 6, lane = tid & 63;
  const int l15 = lane & 15, l4 = lane >> 4;

  __shared__ float mbias[1024];                       // 4 KB
  __shared__ int any_big;
  __shared__ __align__(16) u16 plds[4][32][66];       // 16.5 KB per-wave P
  __shared__ __align__(16) u16 ktile[2][64][64];      // 16 KB dbuf
  __shared__ __align__(16) u16 vtile[2][64][64];      // 16 KB dbuf

  // ---- mask -> additive exp2-domain bias (robust to int32 vs byte bool) ----
  if (tid == 0) any_big = 0;
  __syncthreads();
  {
    const unsigned* mu = (const unsigned*)maskp;
    int loc = 0;
    for (int i = tid; i < 2048; i += 256)
      if (mu[i] > 1u) loc = 1;
    if (loc) atomicOr(&any_big, 1);
  }
  __syncthreads();
  const float CEXP = 23.0831206542234f;  // 16 * log2(e)
  if (any_big) {
    const unsigned char* mb = (const unsigned char*)maskp;
    for (int i = tid; i < 1024; i += 256)
      mbias[i] = mb[b * 1024 + i] ? -100000.0f : -CEXP;
  } else {
    const int* mi_ = (const int*)maskp;
    for (int i = tid; i < 1024; i += 256)
      mbias[i] = mi_[b * 1024 + i] ? -100000.0f : -CEXP;
  }

  const size_t base = (size_t)bh * 65536;
  const int q0 = qt * 128 + w * 32;

  // staging geometry: this thread stages rows (w*8 + lane/8) and +32,
  // LDS 16B-slot lane&7; global col16 pre-swizzled by row&7.
  const int rlo = lane >> 3;
  const int cg = (lane & 7) ^ (rlo & 7);     // (w*8+rlo)&7 == rlo&7
  const int srow = w * 8 + rlo;
  const u16* kg0 = kb + base + (size_t)srow * 64 + cg * 8;    // + kt*4096
  const u16* vg0 = vtb + base + (size_t)srow * 1024 + cg * 8; // + kt*64
  u16* kd = &ktile[0][0][0] + w * 512;       // wave-uniform dest (bytes w*1024)
  u16* vd = &vtile[0][0][0] + w * 512;

  // Q fragments (global, once)
  bf16x8 qf[2][2];
#pragma unroll
  for (int fr = 0; fr < 2; ++fr)
#pragma unroll
    for (int ks = 0; ks < 2; ++ks)
      qf[fr][ks] =
          ld_bf8(qb + base + (size_t)(q0 + fr * 16 + l15) * 64 + ks * 32 + l4 * 8);

  f32x4 o[2][4];
  float ps[2][4];
  const f32x4 vz = {0.f, 0.f, 0.f, 0.f};
#pragma unroll
  for (int fr = 0; fr < 2; ++fr) {
#pragma unroll
    for (int oc = 0; oc < 4; ++oc) o[fr][oc] = vz;
#pragma unroll
    for (int r = 0; r < 4; ++r) ps[fr][r] = 0.f;
  }

  // prologue: stage tile 0 into buffer 0
  glds16(kg0, kd);
  glds16(kg0 + 32 * 64, kd + 2048);
  glds16(vg0, vd);
  glds16(vg0 + 32 * 1024, vd + 2048);
  __syncthreads();

  for (int kt = 0; kt < 16; ++kt) {
    const int cur = kt & 1;
    // async prefetch next tile into the other buffer
    if (kt < 15) {
      const int nxt = cur ^ 1;
      glds16(kg0 + (kt + 1) * 4096, kd + nxt * 4096);
      glds16(kg0 + (kt + 1) * 4096 + 32 * 64, kd + nxt * 4096 + 2048);
      glds16(vg0 + (kt + 1) * 64, vd + nxt * 4096);
      glds16(vg0 + (kt + 1) * 64 + 32 * 1024, vd + nxt * 4096 + 2048);
    }

    float mb4[4];
#pragma unroll
    for (int nc = 0; nc < 4; ++nc) mb4[nc] = mbias[kt * 64 + nc * 16 + l15];

    f32x4 s[2][4];
#pragma unroll
    for (int fr = 0; fr < 2; ++fr)
#pragma unroll
      for (int nc = 0; nc < 4; ++nc) s[fr][nc] = vz;

    // S = Q K^T from swizzled LDS
    const u16* Kl = &ktile[cur][0][0];
#pragma unroll
    for (int nc = 0; nc < 4; ++nc) {
      int row = nc * 16 + l15;
      bf16x8 kf0 = ld_bf8(Kl + row * 64 + (l4 ^ (row & 7)) * 8);
      bf16x8 kf1 = ld_bf8(Kl + row * 64 + ((4 + l4) ^ (row & 7)) * 8);
      s[0][nc] = __builtin_amdgcn_mfma_f32_16x16x32_bf16(qf[0][0], kf0, s[0][nc], 0, 0, 0);
      s[0][nc] = __builtin_amdgcn_mfma_f32_16x16x32_bf16(qf[0][1], kf1, s[0][nc], 0, 0, 0);
      s[1][nc] = __builtin_amdgcn_mfma_f32_16x16x32_bf16(qf[1][0], kf0, s[1][nc], 0, 0, 0);
      s[1][nc] = __builtin_amdgcn_mfma_f32_16x16x32_bf16(qf[1][1], kf1, s[1][nc], 0, 0, 0);
    }

    // p = exp2(s + bias); row partial sums; P -> wave-private LDS (bf16)
#pragma unroll
    for (int fr = 0; fr < 2; ++fr)
#pragma unroll
      for (int nc = 0; nc < 4; ++nc) {
        float mbn = mb4[nc];
#pragma unroll
        for (int r = 0; r < 4; ++r) {
          float p = fexp2(s[fr][nc][r] + mbn);
          ps[fr][r] += p;
          plds[w][fr * 16 + l4 * 4 + r][nc * 16 + l15] = f2bf(p);
        }
      }

    bf16x8 pf[2][2];
#pragma unroll
    for (int fr = 0; fr < 2; ++fr)
#pragma unroll
      for (int ks = 0; ks < 2; ++ks)
        pf[fr][ks] = ld_bf8(&plds[w][fr * 16 + l15][ks * 32 + l4 * 8]);

    // O += P V from swizzled LDS (rows of V^T are d-indices)
    const u16* Vl = &vtile[cur][0][0];
#pragma unroll
    for (int oc = 0; oc < 4; ++oc) {
      int row = oc * 16 + l15;
      bf16x8 vf0 = ld_bf8(Vl + row * 64 + (l4 ^ (row & 7)) * 8);
      bf16x8 vf1 = ld_bf8(Vl + row * 64 + ((4 + l4) ^ (row & 7)) * 8);
      o[0][oc] = __builtin_amdgcn_mfma_f32_16x16x32_bf16(pf[0][0], vf0, o[0][oc], 0, 0, 0);
      o[0][oc] = __builtin_amdgcn_mfma_f32_16x16x32_bf16(pf[0][1], vf1, o[0][oc], 0, 0, 0);
      o[1][oc] = __builtin_amdgcn_mfma_f32_16x16x32_bf16(pf[1][0], vf0, o[1][oc], 0, 0, 0);
      o[1][oc] = __builtin_amdgcn_mfma_f32_16x16x32_bf16(pf[1][1], vf1, o[1][oc], 0, 0, 0);
    }

    __syncthreads();   // staged kt+1 complete; safe to swap buffers
  }

  // row sums: reduce across the 16-lane column group
#pragma unroll
  for (int d = 1; d < 16; d <<= 1)
#pragma unroll
    for (int fr = 0; fr < 2; ++fr)
#pragma unroll
      for (int r = 0; r < 4; ++r)
        ps[fr][r] += __shfl_xor(ps[fr][r], d, 64);

  float inv[2][4];
#pragma unroll
  for (int fr = 0; fr < 2; ++fr)
#pragma unroll
    for (int r = 0; r < 4; ++r) inv[fr][r] = 1.0f / ps[fr][r];

  // stage O (bf16) into wave-private plds, then vector-store to x2
#pragma unroll
  for (int fr = 0; fr < 2; ++fr)
#pragma unroll
    for (int oc = 0; oc < 4; ++oc)
#pragma unroll
      for (int r = 0; r < 4; ++r)
        plds[w][fr * 16 + l4 * 4 + r][oc * 16 + l15] =
            f2bf(o[fr][oc][r] * inv[fr][r]);

  {
    int row2 = lane >> 1, ch = lane & 1;
    const u16* srcp = &plds[w][row2][ch * 32];
    u16x8 t0 = *(const u16x8*)(srcp);
    u16x8 t1 = *(const u16x8*)(srcp + 8);
    u16x8 t2 = *(const u16x8*)(srcp + 16);
    u16x8 t3 = *(const u16x8*)(srcp + 24);
    size_t m = (size_t)b * 1024 + q0 + row2;
    u16* dst = x2 + m * 768 + h * 64 + ch * 32;
    *(u16x8*)dst = t0;
    *(u16x8*)(dst + 8) = t1;
    *(u16x8*)(dst + 16) = t2;
    *(u16x8*)(dst + 24) = t3;
  }
}

// ---------------------------------------------------------------- out proj
__global__ __launch_bounds__(256, 2)
void out_gemm(const u16* __restrict__ A, const u16* __restrict__ W,
              const float* __restrict__ bias, float* __restrict__ out) {
  __shared__ __align__(16) u16 lA[128 * 32];
  __shared__ __align__(16) u16 lB[128 * 32];
  const int tid = threadIdx.x;
  const int lane = tid & 63, wid = tid >> 6;
  const int wm = wid >> 1, wn = wid & 1;
  const int l15 = lane & 15, l4 = lane >> 4;
  const int rowA0 = blockIdx.y * 128, rowB0 = blockIdx.x * 128;

  const u16* ga = A + (size_t)(rowA0 + wid * 32 + (lane >> 2)) * 768 + (lane & 3) * 8;
  const u16* gb = W + (size_t)(rowB0 + wid * 32 + (lane >> 2)) * 768 + (lane & 3) * 8;
  u16* la0 = lA + wid * 1024;
  u16* lb0 = lB + wid * 1024;

  f32x4 acc[4][4];
  const f32x4 vz = {0.f, 0.f, 0.f, 0.f};
#pragma unroll
  for (int i = 0; i < 4; ++i)
#pragma unroll
    for (int j = 0; j < 4; ++j) acc[i][j] = vz;

  for (int k0 = 0; k0 < 768; k0 += 32) {
    glds16(ga + k0,            la0);
    glds16(ga + k0 + 16 * 768, la0 + 512);
    glds16(gb + k0,            lb0);
    glds16(gb + k0 + 16 * 768, lb0 + 512);
    __syncthreads();
    bf16x8 af[4], bfr[4];
#pragma unroll
    for (int mi = 0; mi < 4; ++mi)
      af[mi] = ld_bf8(lA + (wm * 64 + mi * 16 + l15) * 32 + l4 * 8);
#pragma unroll
    for (int ni = 0; ni < 4; ++ni)
      bfr[ni] = ld_bf8(lB + (wn * 64 + ni * 16 + l15) * 32 + l4 * 8);
#pragma unroll
    for (int mi = 0; mi < 4; ++mi)
#pragma unroll
      for (int ni = 0; ni < 4; ++ni)
        acc[mi][ni] = __builtin_amdgcn_mfma_f32_16x16x32_bf16(
            af[mi], bfr[ni], acc[mi][ni], 0, 0, 0);
    __syncthreads();
  }

#pragma unroll
  for (int ni = 0; ni < 4; ++ni) {
    int n = rowB0 + wn * 64 + ni * 16 + l15;
    float bn_ = bias[n];
#pragma unroll
    for (int mi = 0; mi < 4; ++mi)
#pragma unroll
      for (int r = 0; r < 4; ++r) {
        int m = rowA0 + wm * 64 + mi * 16 + l4 * 4 + r;
        out[(size_t)m * 768 + n] = acc[mi][ni][r] + bn_;
      }
  }
}

// ---------------------------------------------------------------- launch
extern "C" void kernel_launch(void* const* d_in, const int* in_sizes, int n_in,
                              void* d_out, int out_size, void* d_ws, size_t ws_size,
                              hipStream_t stream) {
  const float* x    = (const float*)d_in[0];
  const void*  mask = d_in[1];
  const float* wqkv = (const float*)d_in[2];
  const float* bqkv = (const float*)d_in[3];
  const float* wo   = (const float*)d_in[4];
  const float* bo   = (const float*)d_in[5];
  float* out = (float*)d_out;

  u16* ws = (u16*)d_ws;
  u16* xbf   = ws;
  u16* wqkvb = ws + 6291456;
  u16* wob   = ws + 8060928;
  u16* qbuf  = ws + 8650752;
  u16* kbuf  = ws + 14942208;
  u16* vtbuf = ws + 21233664;
  u16* x2buf = ws + 27525120;

  convert_kernel<<<2048, 256, 0, stream>>>(x, wqkv, wo, xbf, wqkvb, wob);
  qkv_gemm<<<dim3(18, 64), 256, 0, stream>>>(xbf, wqkvb, bqkv, qbuf, kbuf, vtbuf);
  attn_kernel<<<dim3(96, 8), 256, 0, stream>>>(qbuf, kbuf, vtbuf, mask, x2buf);
  out_gemm<<<dim3(6, 64), 256, 0, stream>>>(x2buf, wob, bo, out);
}